// Round 1
// baseline (1314.577 us; speedup 1.0000x reference)
//
#include <hip/hip_runtime.h>

#define NN 100000
#define NG 256
#define NE 800000

constexpr int F0 = 114;   // x features
constexpr int F1 = 230;   // layer1 output features
constexpr int F2 = 115;   // layer2 output features
constexpr int LDA0 = 116; // padded stride for aggX / t2 / agg2 (16B-aligned rows)
constexpr int LDH1 = 232; // padded stride for h1

// ---------------- degree / normalization ----------------

__global__ void k_init_deg(float* deg) {
  int i = blockIdx.x * blockDim.x + threadIdx.x;
  if (i < NN) deg[i] = 1.0f;  // self-loop
}

__global__ void k_count(const int* __restrict__ dst, float* deg) {
  int e = blockIdx.x * blockDim.x + threadIdx.x;
  if (e < NE) unsafeAtomicAdd(&deg[dst[e]], 1.0f);
}

__global__ void k_dinv(float* deg) {
  int i = blockIdx.x * blockDim.x + threadIdx.x;
  if (i < NN) deg[i] = rsqrtf(deg[i]);  // deg >= 1
}

// ---------------- self-loop init + edge scatter ----------------

// out[i, :FEAT] = in[i, :FEAT] * dinv[i]^2   (out stride LDA0)
template <int FEAT, int LDIN>
__global__ void k_self(const float* __restrict__ in, const float* __restrict__ dinv,
                       float* __restrict__ out) {
  int i = blockIdx.x;
  int f = threadIdx.x;
  if (f < FEAT) {
    float d = dinv[i];
    out[(size_t)i * LDA0 + f] = in[(size_t)i * LDIN + f] * d * d;
  }
}

// out[dst] += in[src] * dinv[src]*dinv[dst], 32 lanes per edge, 8 edges/block
template <int FEAT, int LDIN>
__global__ void k_scatter(const int* __restrict__ src, const int* __restrict__ dst,
                          const float* __restrict__ dinv,
                          const float* __restrict__ in, float* __restrict__ out) {
  int grp = threadIdx.x >> 5;
  int lane = threadIdx.x & 31;
  int e = blockIdx.x * 8 + grp;
  if (e >= NE) return;
  int s = src[e], d = dst[e];
  float norm = dinv[s] * dinv[d];
  const float* xs = in + (size_t)s * LDIN;
  float* ad = out + (size_t)d * LDA0;
  for (int f = lane; f < FEAT; f += 32)
    unsafeAtomicAdd(&ad[f], xs[f] * norm);
}

// ---------------- fp32 tiled GEMM: C = op(A@B + bias) ----------------

template <bool RELU, bool BIAS>
__global__ __launch_bounds__(256) void k_gemm(
    const float* __restrict__ A, int lda,
    const float* __restrict__ B, int ldb,
    const float* __restrict__ bias,
    float* __restrict__ C, int ldc,
    int M, int N, int K) {
  constexpr int BM = 64, BN = 64, BK = 32, PAD = 4;
  __shared__ float As[BK][BM + PAD];  // transposed A tile: As[k][m]
  __shared__ float Bs[BK][BN + PAD];  // Bs[k][n]
  int tid = threadIdx.x;
  int tx = tid % 16, ty = tid / 16;
  int m0 = blockIdx.y * BM, n0 = blockIdx.x * BN;

  float acc[4][4] = {};

  int la_c = tid % 32;  // k within chunk
  int la_r = tid / 32;  // row, step 8
  int lb_c = tid % 64;  // n
  int lb_r = tid / 64;  // k, step 4

  for (int kt = 0; kt < K; kt += BK) {
#pragma unroll
    for (int i = 0; i < BM; i += 8) {
      int m = m0 + la_r + i;
      int k = kt + la_c;
      float v = (m < M && k < K) ? A[(size_t)m * lda + k] : 0.0f;
      As[la_c][la_r + i] = v;
    }
#pragma unroll
    for (int i = 0; i < BK; i += 4) {
      int k = kt + lb_r + i;
      int n = n0 + lb_c;
      float v = (k < K && n < N) ? B[(size_t)k * ldb + n] : 0.0f;
      Bs[lb_r + i][lb_c] = v;
    }
    __syncthreads();
#pragma unroll
    for (int k = 0; k < BK; ++k) {
      float4 a4 = *reinterpret_cast<const float4*>(&As[k][ty * 4]);
      float4 b4 = *reinterpret_cast<const float4*>(&Bs[k][tx * 4]);
      float av[4] = {a4.x, a4.y, a4.z, a4.w};
      float bv[4] = {b4.x, b4.y, b4.z, b4.w};
#pragma unroll
      for (int i = 0; i < 4; ++i)
#pragma unroll
        for (int j = 0; j < 4; ++j) acc[i][j] += av[i] * bv[j];
    }
    __syncthreads();
  }

#pragma unroll
  for (int i = 0; i < 4; ++i) {
    int m = m0 + ty * 4 + i;
    if (m >= M) continue;
#pragma unroll
    for (int j = 0; j < 4; ++j) {
      int n = n0 + tx * 4 + j;
      if (n >= N) continue;
      float v = acc[i][j];
      if (BIAS) v += bias[n];
      if (RELU) v = fmaxf(v, 0.0f);
      C[(size_t)m * ldc + n] = v;
    }
  }
}

// ---------------- fused relu(agg2+b2) + segmented max-pool ----------------

constexpr int POOL_CHUNK = 256;

__global__ void k_pool(const float* __restrict__ agg2, const float* __restrict__ b2,
                       const int* __restrict__ batch, float* pooled) {
  int f = threadIdx.x;
  if (f >= F2) return;
  float b = b2[f];
  int n0 = blockIdx.x * POOL_CHUNK;
  int n1 = min(n0 + POOL_CHUNK, NN);
  int curg = -1;
  float vmax = 0.0f;  // relu clamp + empty-segment 0
  for (int n = n0; n < n1; ++n) {
    int g = batch[n];  // sorted -> monotone
    if (g != curg) {
      if (curg >= 0 && vmax > 0.0f)
        atomicMax((int*)&pooled[curg * F2 + f], __float_as_int(vmax));
      curg = g;
      vmax = 0.0f;
    }
    float v = agg2[(size_t)n * LDA0 + f] + b;
    vmax = fmaxf(vmax, v);
  }
  if (curg >= 0 && vmax > 0.0f)
    atomicMax((int*)&pooled[curg * F2 + f], __float_as_int(vmax));
}

// ---------------- tiny MLP head: 115 -> 64 -> 32 -> 1 ----------------

__global__ void k_mlp(const float* __restrict__ pooled,
                      const float* __restrict__ Wg, const float* __restrict__ bg,
                      const float* __restrict__ Wf, const float* __restrict__ bf,
                      const float* __restrict__ Wo, const float* __restrict__ bo,
                      float* __restrict__ out) {
  __shared__ float sp[F2];
  __shared__ float sg[64];
  __shared__ float sf[32];
  int g = blockIdx.x, t = threadIdx.x;
  for (int f = t; f < F2; f += 64) sp[f] = pooled[g * F2 + f];
  __syncthreads();
  float a = bg[t];
  for (int k = 0; k < F2; ++k) a += sp[k] * Wg[k * 64 + t];
  sg[t] = fmaxf(a, 0.0f);
  __syncthreads();
  if (t < 32) {
    float c = bf[t];
    for (int k = 0; k < 64; ++k) c += sg[k] * Wf[k * 32 + t];
    sf[t] = fmaxf(c, 0.0f);
  }
  __syncthreads();
  if (t == 0) {
    float c = bo[0];
    for (int k = 0; k < 32; ++k) c += sf[k] * Wo[k];
    out[g] = c;
  }
}

// ---------------- launch ----------------

extern "C" void kernel_launch(void* const* d_in, const int* in_sizes, int n_in,
                              void* d_out, int out_size, void* d_ws, size_t ws_size,
                              hipStream_t stream) {
  const float* x  = (const float*)d_in[0];
  const int* ei   = (const int*)d_in[1];
  const int* batch = (const int*)d_in[2];
  const float* W1 = (const float*)d_in[3];
  const float* b1 = (const float*)d_in[4];
  const float* W2 = (const float*)d_in[5];
  const float* b2 = (const float*)d_in[6];
  const float* Wg = (const float*)d_in[7];
  const float* bg = (const float*)d_in[8];
  const float* Wf = (const float*)d_in[9];
  const float* bf = (const float*)d_in[10];
  const float* Wo = (const float*)d_in[11];
  const float* bo = (const float*)d_in[12];
  const int* src = ei;
  const int* dst = ei + NE;

  float* ws = (float*)d_ws;
  float* deg    = ws;                       // 100224 (rounded up)
  float* bufA   = deg + 100224;             // aggX, later t2: NN*116
  float* h1     = bufA + (size_t)NN * LDA0; // NN*232
  float* agg2   = h1 + (size_t)NN * LDH1;   // NN*116
  float* pooled = agg2 + (size_t)NN * LDA0; // NG*F2

  hipMemsetAsync(pooled, 0, (size_t)NG * F2 * sizeof(float), stream);

  k_init_deg<<<(NN + 255) / 256, 256, 0, stream>>>(deg);
  k_count<<<(NE + 255) / 256, 256, 0, stream>>>(dst, deg);
  k_dinv<<<(NN + 255) / 256, 256, 0, stream>>>(deg);

  // layer 1: aggregate X (114-wide), then GEMM+bias+relu
  k_self<F0, F0><<<NN, 128, 0, stream>>>(x, deg, bufA);
  k_scatter<F0, F0><<<NE / 8, 256, 0, stream>>>(src, dst, deg, x, bufA);
  k_gemm<true, true><<<dim3(4, (NN + 63) / 64), 256, 0, stream>>>(
      bufA, LDA0, W1, F1, b1, h1, LDH1, NN, F1, F0);

  // layer 2: GEMM first (115-wide output), then aggregate
  k_gemm<false, false><<<dim3(2, (NN + 63) / 64), 256, 0, stream>>>(
      h1, LDH1, W2, F2, nullptr, bufA, LDA0, NN, F2, F1);
  k_self<F2, LDA0><<<NN, 128, 0, stream>>>(bufA, deg, agg2);
  k_scatter<F2, LDA0><<<NE / 8, 256, 0, stream>>>(src, dst, deg, bufA, agg2);

  // fused relu(agg2 + b2) + per-graph max pool
  k_pool<<<(NN + POOL_CHUNK - 1) / POOL_CHUNK, 128, 0, stream>>>(agg2, b2, batch, pooled);

  // head MLP
  k_mlp<<<NG, 64, 0, stream>>>(pooled, Wg, bg, Wf, bf, Wo, bo, (float*)d_out);
}

// Round 2
// 670.787 us; speedup vs baseline: 1.9598x; 1.9598x over previous
//
#include <hip/hip_runtime.h>

#define NN 100000
#define NG 256
#define NE 800000

constexpr int F0 = 114;   // x features
constexpr int F1 = 230;   // layer1 output features
constexpr int F2 = 115;   // layer2 output features
constexpr int LDA0 = 116; // padded stride for aggX / t2 / agg2
constexpr int LDH1 = 232; // padded stride for h1

// ---------------- degree / CSR build ----------------

__global__ void k_count(const int* __restrict__ dst, int* __restrict__ cnt) {
  int e = blockIdx.x * blockDim.x + threadIdx.x;
  if (e < NE) atomicAdd(&cnt[dst[e]], 1);
}

__global__ void k_dinv(const int* __restrict__ cnt, float* __restrict__ dinv) {
  int i = blockIdx.x * blockDim.x + threadIdx.x;
  if (i < NN) dinv[i] = rsqrtf((float)cnt[i] + 1.0f);  // +1 self-loop
}

constexpr int SCAN_T = 256;
constexpr int SCAN_E = 1024;                       // elements per scan block
constexpr int NB = (NN + SCAN_E - 1) / SCAN_E;     // 98

__global__ void k_scan1(const int* __restrict__ cnt, int* __restrict__ off,
                        int* __restrict__ bsum) {
  __shared__ int s[SCAN_T];
  int b = blockIdx.x, t = threadIdx.x;
  int base = b * SCAN_E + t * 4;
  int v0 = 0, v1 = 0, v2 = 0, v3 = 0;
  if (base + 0 < NN) v0 = cnt[base + 0];
  if (base + 1 < NN) v1 = cnt[base + 1];
  if (base + 2 < NN) v2 = cnt[base + 2];
  if (base + 3 < NN) v3 = cnt[base + 3];
  int sum = v0 + v1 + v2 + v3;
  s[t] = sum;
  __syncthreads();
  for (int ofs = 1; ofs < SCAN_T; ofs <<= 1) {
    int x = (t >= ofs) ? s[t - ofs] : 0;
    __syncthreads();
    s[t] += x;
    __syncthreads();
  }
  int excl = s[t] - sum;  // exclusive prefix of this thread's 4 elems
  if (base + 0 < NN) off[base + 0] = excl;
  if (base + 1 < NN) off[base + 1] = excl + v0;
  if (base + 2 < NN) off[base + 2] = excl + v0 + v1;
  if (base + 3 < NN) off[base + 3] = excl + v0 + v1 + v2;
  if (t == SCAN_T - 1) bsum[b] = s[t];
}

__global__ void k_scan2(int* bsum) {  // exclusive scan of 98 block sums
  if (threadIdx.x == 0) {
    int run = 0;
    for (int i = 0; i < NB; ++i) { int v = bsum[i]; bsum[i] = run; run += v; }
  }
}

__global__ void k_scan3(int* __restrict__ off, const int* __restrict__ bsum,
                        int* __restrict__ cur) {
  int i = blockIdx.x * blockDim.x + threadIdx.x;
  if (i < NN) {
    int v = off[i] + bsum[i / SCAN_E];
    off[i] = v;
    cur[i] = v;
  }
  if (i == NN) off[NN] = NE;
}

__global__ void k_place(const int* __restrict__ src, const int* __restrict__ dst,
                        const float* __restrict__ dinv, int* __restrict__ cur,
                        int* __restrict__ srcs, float* __restrict__ norms) {
  int e = blockIdx.x * blockDim.x + threadIdx.x;
  if (e >= NE) return;
  int s = src[e], d = dst[e];
  int p = atomicAdd(&cur[d], 1);
  srcs[p] = s;
  norms[p] = dinv[s] * dinv[d];
}

// ---------------- per-node gather-reduce (replaces scatter) ----------------
// out[n,f] = in[n,f]*dinv[n]^2 + sum_{j in csr[n]} in[srcs[j],f]*norms[j]

template <int FEAT, int LDIN>
__global__ void k_gather(const float* __restrict__ in, const float* __restrict__ dinv,
                         const int* __restrict__ off, const int* __restrict__ srcs,
                         const float* __restrict__ norms, float* __restrict__ out) {
  int n = blockIdx.x;
  int f = threadIdx.x;
  if (f >= FEAT) return;
  float d = dinv[n];
  float acc = in[(size_t)n * LDIN + f] * d * d;
  int j0 = off[n], j1 = off[n + 1];
  for (int j = j0; j < j1; ++j)
    acc += in[(size_t)srcs[j] * LDIN + f] * norms[j];
  out[(size_t)n * LDA0 + f] = acc;
}

// ---------------- fp32 tiled GEMM: C = op(A@B + bias) ----------------

template <bool RELU, bool BIAS>
__global__ __launch_bounds__(256) void k_gemm(
    const float* __restrict__ A, int lda,
    const float* __restrict__ B, int ldb,
    const float* __restrict__ bias,
    float* __restrict__ C, int ldc,
    int M, int N, int K) {
  constexpr int BM = 64, BN = 64, BK = 32, PAD = 4;
  __shared__ float As[BK][BM + PAD];
  __shared__ float Bs[BK][BN + PAD];
  int tid = threadIdx.x;
  int tx = tid % 16, ty = tid / 16;
  int m0 = blockIdx.y * BM, n0 = blockIdx.x * BN;

  float acc[4][4] = {};

  int la_c = tid % 32;
  int la_r = tid / 32;
  int lb_c = tid % 64;
  int lb_r = tid / 64;

  for (int kt = 0; kt < K; kt += BK) {
#pragma unroll
    for (int i = 0; i < BM; i += 8) {
      int m = m0 + la_r + i;
      int k = kt + la_c;
      float v = (m < M && k < K) ? A[(size_t)m * lda + k] : 0.0f;
      As[la_c][la_r + i] = v;
    }
#pragma unroll
    for (int i = 0; i < BK; i += 4) {
      int k = kt + lb_r + i;
      int n = n0 + lb_c;
      float v = (k < K && n < N) ? B[(size_t)k * ldb + n] : 0.0f;
      Bs[lb_r + i][lb_c] = v;
    }
    __syncthreads();
#pragma unroll
    for (int k = 0; k < BK; ++k) {
      float4 a4 = *reinterpret_cast<const float4*>(&As[k][ty * 4]);
      float4 b4 = *reinterpret_cast<const float4*>(&Bs[k][tx * 4]);
      float av[4] = {a4.x, a4.y, a4.z, a4.w};
      float bv[4] = {b4.x, b4.y, b4.z, b4.w};
#pragma unroll
      for (int i = 0; i < 4; ++i)
#pragma unroll
        for (int j = 0; j < 4; ++j) acc[i][j] += av[i] * bv[j];
    }
    __syncthreads();
  }

#pragma unroll
  for (int i = 0; i < 4; ++i) {
    int m = m0 + ty * 4 + i;
    if (m >= M) continue;
#pragma unroll
    for (int j = 0; j < 4; ++j) {
      int n = n0 + tx * 4 + j;
      if (n >= N) continue;
      float v = acc[i][j];
      if (BIAS) v += bias[n];
      if (RELU) v = fmaxf(v, 0.0f);
      C[(size_t)m * ldc + n] = v;
    }
  }
}

// ---------------- fused relu(agg2+b2) + segmented max-pool ----------------

constexpr int POOL_CHUNK = 256;

__global__ void k_pool(const float* __restrict__ agg2, const float* __restrict__ b2,
                       const int* __restrict__ batch, float* pooled) {
  int f = threadIdx.x;
  if (f >= F2) return;
  float b = b2[f];
  int n0 = blockIdx.x * POOL_CHUNK;
  int n1 = min(n0 + POOL_CHUNK, NN);
  int curg = -1;
  float vmax = 0.0f;
  for (int n = n0; n < n1; ++n) {
    int g = batch[n];
    if (g != curg) {
      if (curg >= 0 && vmax > 0.0f)
        atomicMax((int*)&pooled[curg * F2 + f], __float_as_int(vmax));
      curg = g;
      vmax = 0.0f;
    }
    float v = agg2[(size_t)n * LDA0 + f] + b;
    vmax = fmaxf(vmax, v);
  }
  if (curg >= 0 && vmax > 0.0f)
    atomicMax((int*)&pooled[curg * F2 + f], __float_as_int(vmax));
}

// ---------------- tiny MLP head: 115 -> 64 -> 32 -> 1 ----------------

__global__ void k_mlp(const float* __restrict__ pooled,
                      const float* __restrict__ Wg, const float* __restrict__ bg,
                      const float* __restrict__ Wf, const float* __restrict__ bf,
                      const float* __restrict__ Wo, const float* __restrict__ bo,
                      float* __restrict__ out) {
  __shared__ float sp[F2];
  __shared__ float sg[64];
  __shared__ float sf[32];
  int g = blockIdx.x, t = threadIdx.x;
  for (int f = t; f < F2; f += 64) sp[f] = pooled[g * F2 + f];
  __syncthreads();
  float a = bg[t];
  for (int k = 0; k < F2; ++k) a += sp[k] * Wg[k * 64 + t];
  sg[t] = fmaxf(a, 0.0f);
  __syncthreads();
  if (t < 32) {
    float c = bf[t];
    for (int k = 0; k < 64; ++k) c += sg[k] * Wf[k * 32 + t];
    sf[t] = fmaxf(c, 0.0f);
  }
  __syncthreads();
  if (t == 0) {
    float c = bo[0];
    for (int k = 0; k < 32; ++k) c += sf[k] * Wo[k];
    out[g] = c;
  }
}

// ---------------- launch ----------------

extern "C" void kernel_launch(void* const* d_in, const int* in_sizes, int n_in,
                              void* d_out, int out_size, void* d_ws, size_t ws_size,
                              hipStream_t stream) {
  const float* x  = (const float*)d_in[0];
  const int* ei   = (const int*)d_in[1];
  const int* batch = (const int*)d_in[2];
  const float* W1 = (const float*)d_in[3];
  const float* b1 = (const float*)d_in[4];
  const float* W2 = (const float*)d_in[5];
  const float* b2 = (const float*)d_in[6];
  const float* Wg = (const float*)d_in[7];
  const float* bg = (const float*)d_in[8];
  const float* Wf = (const float*)d_in[9];
  const float* bf = (const float*)d_in[10];
  const float* Wo = (const float*)d_in[11];
  const float* bo = (const float*)d_in[12];
  const int* src = ei;
  const int* dst = ei + NE;

  char* p = (char*)d_ws;
  auto alloc = [&](size_t elems) { void* r = p; p += elems * 4; return r; };
  float* dinv  = (float*)alloc(100224);
  int* cnt     = (int*)alloc(100224);
  int* off     = (int*)alloc(100352);
  int* cur     = (int*)alloc(100224);
  int* bsum    = (int*)alloc(128);
  int* srcs    = (int*)alloc(NE);
  float* norms = (float*)alloc(NE);
  float* bufA  = (float*)alloc((size_t)NN * LDA0);  // aggX, then t2
  float* h1    = (float*)alloc((size_t)NN * LDH1);
  float* agg2  = (float*)alloc((size_t)NN * LDA0);
  float* pooled= (float*)alloc((size_t)NG * F2);

  hipMemsetAsync(cnt, 0, 100224 * sizeof(int), stream);
  hipMemsetAsync(pooled, 0, (size_t)NG * F2 * sizeof(float), stream);

  // CSR build (shared by both conv layers)
  k_count<<<(NE + 255) / 256, 256, 0, stream>>>(dst, cnt);
  k_dinv<<<(NN + 255) / 256, 256, 0, stream>>>(cnt, dinv);
  k_scan1<<<NB, SCAN_T, 0, stream>>>(cnt, off, bsum);
  k_scan2<<<1, 64, 0, stream>>>(bsum);
  k_scan3<<<(NN + 256) / 256, 256, 0, stream>>>(off, bsum, cur);
  k_place<<<(NE + 255) / 256, 256, 0, stream>>>(src, dst, dinv, cur, srcs, norms);

  // layer 1: aggregate X (114-wide) via gather, then GEMM+bias+relu
  k_gather<F0, F0><<<NN, 128, 0, stream>>>(x, dinv, off, srcs, norms, bufA);
  k_gemm<true, true><<<dim3(4, (NN + 63) / 64), 256, 0, stream>>>(
      bufA, LDA0, W1, F1, b1, h1, LDH1, NN, F1, F0);

  // layer 2: GEMM first (115-wide output), then aggregate via gather
  k_gemm<false, false><<<dim3(2, (NN + 63) / 64), 256, 0, stream>>>(
      h1, LDH1, W2, F2, nullptr, bufA, LDA0, NN, F2, F1);
  k_gather<F2, LDA0><<<NN, 128, 0, stream>>>(bufA, dinv, off, srcs, norms, agg2);

  // fused relu(agg2 + b2) + per-graph max pool
  k_pool<<<(NN + POOL_CHUNK - 1) / POOL_CHUNK, 128, 0, stream>>>(agg2, b2, batch, pooled);

  // head MLP
  k_mlp<<<NG, 64, 0, stream>>>(pooled, Wg, bg, Wf, bf, Wo, bo, (float*)d_out);
}

// Round 3
// 568.088 us; speedup vs baseline: 2.3140x; 1.1808x over previous
//
#include <hip/hip_runtime.h>
#include <hip/hip_bf16.h>

#define NN 100000
#define NG 256
#define NE 800000

constexpr int F0 = 114;   // x features
constexpr int F1 = 230;   // layer1 output features
constexpr int F2 = 115;   // layer2 output features
constexpr int MPAD = 100096;  // 782 * 128

typedef __attribute__((ext_vector_type(8))) short s8b;        // 8 bf16 (MFMA operand)
typedef __attribute__((ext_vector_type(4))) float f32x4;      // MFMA acc
typedef __attribute__((ext_vector_type(8))) unsigned short u16x8;

__device__ __forceinline__ unsigned short f2bf(float x) {
  __hip_bfloat16 h = __float2bfloat16(x);
  return *(unsigned short*)&h;
}
__device__ __forceinline__ float bf2f(unsigned short u) {
  __hip_bfloat16 h = *(__hip_bfloat16*)&u;
  return __bfloat162float(h);
}

// ---------------- degree / CSR build ----------------

__global__ void k_count(const int* __restrict__ dst, int* __restrict__ cnt) {
  int e = blockIdx.x * blockDim.x + threadIdx.x;
  if (e < NE) atomicAdd(&cnt[dst[e]], 1);
}

__global__ void k_dinv(const int* __restrict__ cnt, float* __restrict__ dinv) {
  int i = blockIdx.x * blockDim.x + threadIdx.x;
  if (i < NN) dinv[i] = rsqrtf((float)cnt[i] + 1.0f);
}

constexpr int SCAN_T = 256;
constexpr int SCAN_E = 1024;
constexpr int NB = (NN + SCAN_E - 1) / SCAN_E;  // 98

__global__ void k_scan1(const int* __restrict__ cnt, int* __restrict__ off,
                        int* __restrict__ bsum) {
  __shared__ int s[SCAN_T];
  int b = blockIdx.x, t = threadIdx.x;
  int base = b * SCAN_E + t * 4;
  int v0 = 0, v1 = 0, v2 = 0, v3 = 0;
  if (base + 0 < NN) v0 = cnt[base + 0];
  if (base + 1 < NN) v1 = cnt[base + 1];
  if (base + 2 < NN) v2 = cnt[base + 2];
  if (base + 3 < NN) v3 = cnt[base + 3];
  int sum = v0 + v1 + v2 + v3;
  s[t] = sum;
  __syncthreads();
  for (int ofs = 1; ofs < SCAN_T; ofs <<= 1) {
    int x = (t >= ofs) ? s[t - ofs] : 0;
    __syncthreads();
    s[t] += x;
    __syncthreads();
  }
  int excl = s[t] - sum;
  if (base + 0 < NN) off[base + 0] = excl;
  if (base + 1 < NN) off[base + 1] = excl + v0;
  if (base + 2 < NN) off[base + 2] = excl + v0 + v1;
  if (base + 3 < NN) off[base + 3] = excl + v0 + v1 + v2;
  if (t == SCAN_T - 1) bsum[b] = s[t];
}

__global__ void k_scan2(int* bsum) {
  if (threadIdx.x == 0) {
    int run = 0;
    for (int i = 0; i < NB; ++i) { int v = bsum[i]; bsum[i] = run; run += v; }
  }
}

__global__ void k_scan3(int* __restrict__ off, const int* __restrict__ bsum,
                        int* __restrict__ cur) {
  int i = blockIdx.x * blockDim.x + threadIdx.x;
  if (i < NN) {
    int v = off[i] + bsum[i / SCAN_E];
    off[i] = v;
    cur[i] = v;
  }
  if (i == NN) off[NN] = NE;
}

__global__ void k_place(const int* __restrict__ src, const int* __restrict__ dst,
                        const float* __restrict__ dinv, int* __restrict__ cur,
                        int* __restrict__ srcs, float* __restrict__ norms) {
  int e = blockIdx.x * blockDim.x + threadIdx.x;
  if (e >= NE) return;
  int s = src[e], d = dst[e];
  int p = atomicAdd(&cur[d], 1);
  srcs[p] = s;
  norms[p] = dinv[s] * dinv[d];
}

// ---------------- gather-reduce, bf16 hi/lo output (layer 1 input) ----------------
// out[n][0..127]: f<114: agg value split; f>=114: zero pad

__global__ void k_gather_split(const float* __restrict__ in, const float* __restrict__ dinv,
                               const int* __restrict__ off, const int* __restrict__ srcs,
                               const float* __restrict__ norms,
                               unsigned short* __restrict__ oh, unsigned short* __restrict__ ol) {
  int n = blockIdx.x, f = threadIdx.x;  // 128 threads
  float acc = 0.0f;
  if (f < F0) {
    float d = dinv[n];
    acc = in[(size_t)n * F0 + f] * d * d;
    int j0 = off[n], j1 = off[n + 1];
    for (int j = j0; j < j1; ++j)
      acc += in[(size_t)srcs[j] * F0 + f] * norms[j];
  }
  unsigned short h = f2bf(acc);
  unsigned short l = f2bf(acc - bf2f(h));
  oh[(size_t)n * 128 + f] = h;
  ol[(size_t)n * 128 + f] = l;
}

// ---------------- gather-reduce, f32 (layer 2, post-GEMM) ----------------

__global__ void k_gather_f32(const float* __restrict__ in, const float* __restrict__ dinv,
                             const int* __restrict__ off, const int* __restrict__ srcs,
                             const float* __restrict__ norms, float* __restrict__ out) {
  int n = blockIdx.x, f = threadIdx.x;  // 128 threads
  if (f >= F2) return;
  float d = dinv[n];
  float acc = in[(size_t)n * 128 + f] * d * d;
  int j0 = off[n], j1 = off[n + 1];
  for (int j = j0; j < j1; ++j)
    acc += in[(size_t)srcs[j] * 128 + f] * norms[j];
  out[(size_t)n * 128 + f] = acc;
}

// ---------------- weight split+transpose prep: Bt[n][k] ----------------

__global__ void k_prepB(const float* __restrict__ W, unsigned short* __restrict__ Bh,
                        unsigned short* __restrict__ Bl, int K, int N, int KP) {
  int n = blockIdx.x, k = threadIdx.x;  // blockDim.x == KP
  float v = (k < K && n < N) ? W[(size_t)k * N + n] : 0.0f;
  unsigned short h = f2bf(v);
  unsigned short l = f2bf(v - bf2f(h));
  Bh[(size_t)n * KP + k] = h;
  Bl[(size_t)n * KP + k] = l;
}

// ---------------- bf16x3 MFMA GEMM: C = A @ Bt^T (+bias, relu, split) ----------------
// A: [MPAD][KP] bf16 hi/lo, Bt: [n][KP] bf16 hi/lo. 128x128 tile, 4 waves.

template <int KCH, bool SPLIT>
__global__ __launch_bounds__(256) void k_mgemm(
    const unsigned short* __restrict__ Ah, const unsigned short* __restrict__ Al,
    const unsigned short* __restrict__ Bh, const unsigned short* __restrict__ Bl,
    const float* __restrict__ bias, int Nvalid, int M,
    float* __restrict__ Cf, unsigned short* __restrict__ Ch, unsigned short* __restrict__ Cl) {
  constexpr int KP = KCH * 128;
  constexpr int LD = 136;  // ushort stride: 272B rows -> 2-way bank aliasing (free)
  __shared__ unsigned short Ash[128 * LD];
  __shared__ unsigned short Asl[128 * LD];
  __shared__ unsigned short Bsh[128 * LD];
  __shared__ unsigned short Bsl[128 * LD];

  int t = threadIdx.x;
  int m0 = blockIdx.y * 128, n0 = blockIdx.x * 128;
  int lane = t & 63, w = t >> 6;
  int wr = (w >> 1) * 64, wc = (w & 1) * 64;
  int r = lane & 15, kb = (lane >> 4) * 8;

  f32x4 acc[4][4];
#pragma unroll
  for (int i = 0; i < 4; ++i)
#pragma unroll
    for (int j = 0; j < 4; ++j) acc[i][j] = (f32x4){0.f, 0.f, 0.f, 0.f};

  for (int kc = 0; kc < KCH; ++kc) {
    if (kc) __syncthreads();
    // stage A/B chunk (128 k-cols) into LDS, reg-staged with padded stride
#pragma unroll
    for (int it = 0; it < 2; ++it) {
      int u = t + it * 256;          // 512 row-quarters
      int row = u >> 2, q = u & 3;   // quarter = 32 bf16 = 64B
      size_t ga = (size_t)(m0 + row) * KP + kc * 128 + q * 32;
      size_t gb = (size_t)(n0 + row) * KP + kc * 128 + q * 32;
      int lo = row * LD + q * 32;
#pragma unroll
      for (int v = 0; v < 4; ++v) {
        *(u16x8*)&Ash[lo + v * 8] = *(const u16x8*)&Ah[ga + v * 8];
        *(u16x8*)&Asl[lo + v * 8] = *(const u16x8*)&Al[ga + v * 8];
        *(u16x8*)&Bsh[lo + v * 8] = *(const u16x8*)&Bh[gb + v * 8];
        *(u16x8*)&Bsl[lo + v * 8] = *(const u16x8*)&Bl[gb + v * 8];
      }
    }
    __syncthreads();

#pragma unroll
    for (int ks = 0; ks < 4; ++ks) {
      int col = ks * 32 + kb;
      s8b ah[4], al[4], bh[4], bl[4];
#pragma unroll
      for (int i = 0; i < 4; ++i) {
        ah[i] = *(const s8b*)&Ash[(wr + i * 16 + r) * LD + col];
        al[i] = *(const s8b*)&Asl[(wr + i * 16 + r) * LD + col];
        bh[i] = *(const s8b*)&Bsh[(wc + i * 16 + r) * LD + col];
        bl[i] = *(const s8b*)&Bsl[(wc + i * 16 + r) * LD + col];
      }
      // 3 passes, small terms first; 16-MFMA reuse distance per acc
#pragma unroll
      for (int i = 0; i < 4; ++i)
#pragma unroll
        for (int j = 0; j < 4; ++j)
          acc[i][j] = __builtin_amdgcn_mfma_f32_16x16x32_bf16(ah[i], bl[j], acc[i][j], 0, 0, 0);
#pragma unroll
      for (int i = 0; i < 4; ++i)
#pragma unroll
        for (int j = 0; j < 4; ++j)
          acc[i][j] = __builtin_amdgcn_mfma_f32_16x16x32_bf16(al[i], bh[j], acc[i][j], 0, 0, 0);
#pragma unroll
      for (int i = 0; i < 4; ++i)
#pragma unroll
        for (int j = 0; j < 4; ++j)
          acc[i][j] = __builtin_amdgcn_mfma_f32_16x16x32_bf16(ah[i], bh[j], acc[i][j], 0, 0, 0);
    }
  }

  // epilogue: C/D layout col = lane&15, row = (lane>>4)*4 + q  [m89/m91]
  int rq = (lane >> 4) * 4;
#pragma unroll
  for (int i = 0; i < 4; ++i) {
#pragma unroll
    for (int j = 0; j < 4; ++j) {
      int n = n0 + wc + j * 16 + r;
#pragma unroll
      for (int q = 0; q < 4; ++q) {
        int m = m0 + wr + i * 16 + rq + q;
        if (m >= M) continue;
        float v = acc[i][j][q];
        if constexpr (SPLIT) {
          v = (n < Nvalid) ? fmaxf(v + bias[n], 0.0f) : 0.0f;
          unsigned short h = f2bf(v);
          unsigned short l = f2bf(v - bf2f(h));
          Ch[(size_t)m * 256 + n] = h;
          Cl[(size_t)m * 256 + n] = l;
        } else {
          Cf[(size_t)m * 128 + n] = v;
        }
      }
    }
  }
}

// ---------------- fused relu(agg2+b2) + segmented max-pool ----------------

constexpr int POOL_CHUNK = 256;

__global__ void k_pool(const float* __restrict__ agg2, const float* __restrict__ b2,
                       const int* __restrict__ batch, float* pooled) {
  int f = threadIdx.x;
  if (f >= F2) return;
  float b = b2[f];
  int n0 = blockIdx.x * POOL_CHUNK;
  int n1 = min(n0 + POOL_CHUNK, NN);
  int curg = -1;
  float vmax = 0.0f;
  for (int n = n0; n < n1; ++n) {
    int g = batch[n];
    if (g != curg) {
      if (curg >= 0 && vmax > 0.0f)
        atomicMax((int*)&pooled[curg * F2 + f], __float_as_int(vmax));
      curg = g;
      vmax = 0.0f;
    }
    float v = agg2[(size_t)n * 128 + f] + b;
    vmax = fmaxf(vmax, v);
  }
  if (curg >= 0 && vmax > 0.0f)
    atomicMax((int*)&pooled[curg * F2 + f], __float_as_int(vmax));
}

// ---------------- tiny MLP head: 115 -> 64 -> 32 -> 1 ----------------

__global__ void k_mlp(const float* __restrict__ pooled,
                      const float* __restrict__ Wg, const float* __restrict__ bg,
                      const float* __restrict__ Wf, const float* __restrict__ bf,
                      const float* __restrict__ Wo, const float* __restrict__ bo,
                      float* __restrict__ out) {
  __shared__ float sp[F2];
  __shared__ float sg[64];
  __shared__ float sf[32];
  int g = blockIdx.x, t = threadIdx.x;
  for (int f = t; f < F2; f += 64) sp[f] = pooled[g * F2 + f];
  __syncthreads();
  float a = bg[t];
  for (int k = 0; k < F2; ++k) a += sp[k] * Wg[k * 64 + t];
  sg[t] = fmaxf(a, 0.0f);
  __syncthreads();
  if (t < 32) {
    float c = bf[t];
    for (int k = 0; k < 64; ++k) c += sg[k] * Wf[k * 32 + t];
    sf[t] = fmaxf(c, 0.0f);
  }
  __syncthreads();
  if (t == 0) {
    float c = bo[0];
    for (int k = 0; k < 32; ++k) c += sf[k] * Wo[k];
    out[g] = c;
  }
}

// ---------------- launch ----------------

extern "C" void kernel_launch(void* const* d_in, const int* in_sizes, int n_in,
                              void* d_out, int out_size, void* d_ws, size_t ws_size,
                              hipStream_t stream) {
  const float* x  = (const float*)d_in[0];
  const int* ei   = (const int*)d_in[1];
  const int* batch = (const int*)d_in[2];
  const float* W1 = (const float*)d_in[3];
  const float* b1 = (const float*)d_in[4];
  const float* W2 = (const float*)d_in[5];
  const float* b2 = (const float*)d_in[6];
  const float* Wg = (const float*)d_in[7];
  const float* bg = (const float*)d_in[8];
  const float* Wf = (const float*)d_in[9];
  const float* bf = (const float*)d_in[10];
  const float* Wo = (const float*)d_in[11];
  const float* bo = (const float*)d_in[12];
  const int* src = ei;
  const int* dst = ei + NE;

  char* p = (char*)d_ws;
  auto alloc4 = [&](size_t units) { void* r = p; p += units * 4; return r; };
  float* dinv  = (float*)alloc4(100224);
  int* cnt     = (int*)alloc4(100224);
  int* off     = (int*)alloc4(100352);
  int* cur     = (int*)alloc4(100224);
  int* bsum    = (int*)alloc4(128);
  int* srcs    = (int*)alloc4(NE);
  float* norms = (float*)alloc4(NE);
  unsigned short* A1h = (unsigned short*)alloc4((size_t)MPAD * 128 / 2);  // 25.6MB
  unsigned short* A1l = (unsigned short*)alloc4((size_t)MPAD * 128 / 2);
  unsigned short* Bt1h = (unsigned short*)alloc4(256 * 128 / 2);
  unsigned short* Bt1l = (unsigned short*)alloc4(256 * 128 / 2);
  unsigned short* Bt2h = (unsigned short*)alloc4(128 * 256 / 2);
  unsigned short* Bt2l = (unsigned short*)alloc4(128 * 256 / 2);
  unsigned short* h1h = (unsigned short*)alloc4((size_t)MPAD * 256 / 2);  // 51.2MB
  unsigned short* h1l = (unsigned short*)alloc4((size_t)MPAD * 256 / 2);
  float* t2     = (float*)alloc4((size_t)MPAD * 128);                     // 51.2MB
  float* pooled = (float*)alloc4((size_t)NG * F2);
  float* agg2   = (float*)A1h;  // alias: A1 dead after GEMM1; 51.2MB spans A1h+A1l

  hipMemsetAsync(cnt, 0, 100224 * sizeof(int), stream);
  hipMemsetAsync(pooled, 0, (size_t)NG * F2 * sizeof(float), stream);

  // CSR build (shared by both conv layers)
  k_count<<<(NE + 255) / 256, 256, 0, stream>>>(dst, cnt);
  k_dinv<<<(NN + 255) / 256, 256, 0, stream>>>(cnt, dinv);
  k_scan1<<<NB, SCAN_T, 0, stream>>>(cnt, off, bsum);
  k_scan2<<<1, 64, 0, stream>>>(bsum);
  k_scan3<<<(NN + 256) / 256, 256, 0, stream>>>(off, bsum, cur);
  k_place<<<(NE + 255) / 256, 256, 0, stream>>>(src, dst, dinv, cur, srcs, norms);

  // weight prep (bf16 hi/lo, transposed, zero-padded)
  k_prepB<<<256, 128, 0, stream>>>(W1, Bt1h, Bt1l, F0, F1, 128);
  k_prepB<<<128, 256, 0, stream>>>(W2, Bt2h, Bt2l, F1, F2, 256);

  // layer 1: aggregate X via gather (bf16-split output), then MFMA GEMM -> h1 hi/lo
  k_gather_split<<<NN, 128, 0, stream>>>(x, dinv, off, srcs, norms, A1h, A1l);
  k_mgemm<1, true><<<dim3(2, MPAD / 128), 256, 0, stream>>>(
      A1h, A1l, Bt1h, Bt1l, b1, F1, NN, nullptr, h1h, h1l);

  // layer 2: MFMA GEMM -> t2 (f32), then aggregate via gather
  k_mgemm<2, false><<<dim3(1, MPAD / 128), 256, 0, stream>>>(
      h1h, h1l, Bt2h, Bt2l, nullptr, F2, NN, t2, nullptr, nullptr);
  k_gather_f32<<<NN, 128, 0, stream>>>(t2, dinv, off, srcs, norms, agg2);

  // fused relu(agg2 + b2) + per-graph max pool
  k_pool<<<(NN + POOL_CHUNK - 1) / POOL_CHUNK, 128, 0, stream>>>(agg2, b2, batch, pooled);

  // head MLP
  k_mlp<<<NG, 64, 0, stream>>>(pooled, Wg, bg, Wf, bf, Wo, bo, (float*)d_out);
}

// Round 4
// 498.566 us; speedup vs baseline: 2.6367x; 1.1394x over previous
//
#include <hip/hip_runtime.h>
#include <hip/hip_bf16.h>

#define NN 100000
#define NG 256
#define NE 800000

constexpr int F0 = 114;   // x features
constexpr int F1 = 230;   // layer1 output features
constexpr int F2 = 115;   // layer2 output features
constexpr int MPAD = 100096;  // 782 * 128

typedef __attribute__((ext_vector_type(8))) short s8b;        // 8 bf16 (MFMA operand)
typedef __attribute__((ext_vector_type(4))) float f32x4;      // MFMA acc
typedef __attribute__((ext_vector_type(8))) unsigned short u16x8;

__device__ __forceinline__ unsigned short f2bf(float x) {
  __hip_bfloat16 h = __float2bfloat16(x);
  return *(unsigned short*)&h;
}
__device__ __forceinline__ float bf2f(unsigned short u) {
  __hip_bfloat16 h = *(__hip_bfloat16*)&u;
  return __bfloat162float(h);
}

// ---------------- degree / CSR build ----------------

__global__ void k_count(const int* __restrict__ dst, int* __restrict__ cnt) {
  int e = blockIdx.x * blockDim.x + threadIdx.x;
  if (e < NE) atomicAdd(&cnt[dst[e]], 1);
}

__global__ void k_dinv(const int* __restrict__ cnt, float* __restrict__ dinv) {
  int i = blockIdx.x * blockDim.x + threadIdx.x;
  if (i < NN) dinv[i] = rsqrtf((float)cnt[i] + 1.0f);
}

constexpr int SCAN_T = 256;
constexpr int SCAN_E = 1024;
constexpr int NB = (NN + SCAN_E - 1) / SCAN_E;  // 98

__global__ void k_scan1(const int* __restrict__ cnt, int* __restrict__ off,
                        int* __restrict__ bsum) {
  __shared__ int s[SCAN_T];
  int b = blockIdx.x, t = threadIdx.x;
  int base = b * SCAN_E + t * 4;
  int v0 = 0, v1 = 0, v2 = 0, v3 = 0;
  if (base + 0 < NN) v0 = cnt[base + 0];
  if (base + 1 < NN) v1 = cnt[base + 1];
  if (base + 2 < NN) v2 = cnt[base + 2];
  if (base + 3 < NN) v3 = cnt[base + 3];
  int sum = v0 + v1 + v2 + v3;
  s[t] = sum;
  __syncthreads();
  for (int ofs = 1; ofs < SCAN_T; ofs <<= 1) {
    int x = (t >= ofs) ? s[t - ofs] : 0;
    __syncthreads();
    s[t] += x;
    __syncthreads();
  }
  int excl = s[t] - sum;
  if (base + 0 < NN) off[base + 0] = excl;
  if (base + 1 < NN) off[base + 1] = excl + v0;
  if (base + 2 < NN) off[base + 2] = excl + v0 + v1;
  if (base + 3 < NN) off[base + 3] = excl + v0 + v1 + v2;
  if (t == SCAN_T - 1) bsum[b] = s[t];
}

__global__ void k_scan2(int* bsum) {
  if (threadIdx.x == 0) {
    int run = 0;
    for (int i = 0; i < NB; ++i) { int v = bsum[i]; bsum[i] = run; run += v; }
  }
}

__global__ void k_scan3(int* __restrict__ off, const int* __restrict__ bsum,
                        int* __restrict__ cur) {
  int i = blockIdx.x * blockDim.x + threadIdx.x;
  if (i < NN) {
    int v = off[i] + bsum[i / SCAN_E];
    off[i] = v;
    cur[i] = v;
  }
  if (i == NN) off[NN] = NE;
}

__global__ void k_place(const int* __restrict__ src, const int* __restrict__ dst,
                        const float* __restrict__ dinv, int* __restrict__ cur,
                        int* __restrict__ srcs, float* __restrict__ norms) {
  int e = blockIdx.x * blockDim.x + threadIdx.x;
  if (e >= NE) return;
  int s = src[e], d = dst[e];
  int p = atomicAdd(&cur[d], 1);
  srcs[p] = s;
  norms[p] = dinv[s] * dinv[d];
}

// ---------------- gather-reduce, bf16 hi/lo output (layer 1 input) ----------------

__global__ void k_gather_split(const float* __restrict__ in, const float* __restrict__ dinv,
                               const int* __restrict__ off, const int* __restrict__ srcs,
                               const float* __restrict__ norms,
                               unsigned short* __restrict__ oh, unsigned short* __restrict__ ol) {
  int n = blockIdx.x, f = threadIdx.x;  // 128 threads
  float acc = 0.0f;
  if (f < F0) {
    float d = dinv[n];
    acc = in[(size_t)n * F0 + f] * d * d;
    int j0 = off[n], j1 = off[n + 1];
    for (int j = j0; j < j1; ++j)
      acc += in[(size_t)srcs[j] * F0 + f] * norms[j];
  }
  unsigned short h = f2bf(acc);
  unsigned short l = f2bf(acc - bf2f(h));
  oh[(size_t)n * 128 + f] = h;
  ol[(size_t)n * 128 + f] = l;
}

// ---------------- gather-reduce, f32 (layer 2, post-GEMM) ----------------

__global__ void k_gather_f32(const float* __restrict__ in, const float* __restrict__ dinv,
                             const int* __restrict__ off, const int* __restrict__ srcs,
                             const float* __restrict__ norms, float* __restrict__ out) {
  int n = blockIdx.x, f = threadIdx.x;  // 128 threads
  if (f >= F2) return;
  float d = dinv[n];
  float acc = in[(size_t)n * 128 + f] * d * d;
  int j0 = off[n], j1 = off[n + 1];
  for (int j = j0; j < j1; ++j)
    acc += in[(size_t)srcs[j] * 128 + f] * norms[j];
  out[(size_t)n * 128 + f] = acc;
}

// ---------------- weight split+transpose prep: Bt[n][k] ----------------

__global__ void k_prepB(const float* __restrict__ W, unsigned short* __restrict__ Bh,
                        unsigned short* __restrict__ Bl, int K, int N, int KP) {
  int n = blockIdx.x, k = threadIdx.x;  // blockDim.x == KP
  float v = (k < K && n < N) ? W[(size_t)k * N + n] : 0.0f;
  unsigned short h = f2bf(v);
  unsigned short l = f2bf(v - bf2f(h));
  Bh[(size_t)n * KP + k] = h;
  Bl[(size_t)n * KP + k] = l;
}

// ---------------- bf16x3 MFMA GEMM: C = A @ Bt^T (+bias, relu, split) ----------------
// A: [MPAD][KP] bf16 hi/lo, Bt: [n][KP] bf16 hi/lo. 128x128 tile, 4 waves.
// BK=64 chunks -> LDS 73.7 KB -> 2 blocks/CU (8 waves) for latency hiding.

template <int KC64, bool SPLIT>
__global__ __launch_bounds__(256) void k_mgemm(
    const unsigned short* __restrict__ Ah, const unsigned short* __restrict__ Al,
    const unsigned short* __restrict__ Bh, const unsigned short* __restrict__ Bl,
    const float* __restrict__ bias, int Nvalid, int M,
    float* __restrict__ Cf, unsigned short* __restrict__ Ch, unsigned short* __restrict__ Cl) {
  constexpr int KP = KC64 * 64;
  constexpr int LD = 72;  // ushort stride: 144B row step = 4 banks -> 2-way (free)
  __shared__ unsigned short Ash[128 * LD];
  __shared__ unsigned short Asl[128 * LD];
  __shared__ unsigned short Bsh[128 * LD];
  __shared__ unsigned short Bsl[128 * LD];

  int t = threadIdx.x;
  int m0 = blockIdx.y * 128, n0 = blockIdx.x * 128;
  int lane = t & 63, w = t >> 6;
  int wr = (w >> 1) * 64, wc = (w & 1) * 64;
  int r = lane & 15, kb = (lane >> 4) * 8;

  f32x4 acc[4][4];
#pragma unroll
  for (int i = 0; i < 4; ++i)
#pragma unroll
    for (int j = 0; j < 4; ++j) acc[i][j] = (f32x4){0.f, 0.f, 0.f, 0.f};

  int srow = t >> 1, shalf = t & 1;  // 128 rows x 2 halves (32 ushort each)
  int slo = srow * LD + shalf * 32;

  for (int kc = 0; kc < KC64; ++kc) {
    if (kc) __syncthreads();
    size_t ga = (size_t)(m0 + srow) * KP + kc * 64 + shalf * 32;
    size_t gb = (size_t)(n0 + srow) * KP + kc * 64 + shalf * 32;
#pragma unroll
    for (int v = 0; v < 4; ++v) {
      *(u16x8*)&Ash[slo + v * 8] = *(const u16x8*)&Ah[ga + v * 8];
      *(u16x8*)&Asl[slo + v * 8] = *(const u16x8*)&Al[ga + v * 8];
      *(u16x8*)&Bsh[slo + v * 8] = *(const u16x8*)&Bh[gb + v * 8];
      *(u16x8*)&Bsl[slo + v * 8] = *(const u16x8*)&Bl[gb + v * 8];
    }
    __syncthreads();

#pragma unroll
    for (int ks = 0; ks < 2; ++ks) {
      int col = ks * 32 + kb;
      s8b ah[4], al[4], bh[4], bl[4];
#pragma unroll
      for (int i = 0; i < 4; ++i) {
        ah[i] = *(const s8b*)&Ash[(wr + i * 16 + r) * LD + col];
        al[i] = *(const s8b*)&Asl[(wr + i * 16 + r) * LD + col];
        bh[i] = *(const s8b*)&Bsh[(wc + i * 16 + r) * LD + col];
        bl[i] = *(const s8b*)&Bsl[(wc + i * 16 + r) * LD + col];
      }
#pragma unroll
      for (int i = 0; i < 4; ++i)
#pragma unroll
        for (int j = 0; j < 4; ++j)
          acc[i][j] = __builtin_amdgcn_mfma_f32_16x16x32_bf16(ah[i], bl[j], acc[i][j], 0, 0, 0);
#pragma unroll
      for (int i = 0; i < 4; ++i)
#pragma unroll
        for (int j = 0; j < 4; ++j)
          acc[i][j] = __builtin_amdgcn_mfma_f32_16x16x32_bf16(al[i], bh[j], acc[i][j], 0, 0, 0);
#pragma unroll
      for (int i = 0; i < 4; ++i)
#pragma unroll
        for (int j = 0; j < 4; ++j)
          acc[i][j] = __builtin_amdgcn_mfma_f32_16x16x32_bf16(ah[i], bh[j], acc[i][j], 0, 0, 0);
    }
  }

  // epilogue: C/D layout col = lane&15, row = (lane>>4)*4 + q  [m89/m91]
  int rq = (lane >> 4) * 4;
#pragma unroll
  for (int i = 0; i < 4; ++i) {
#pragma unroll
    for (int j = 0; j < 4; ++j) {
      int n = n0 + wc + j * 16 + r;
#pragma unroll
      for (int q = 0; q < 4; ++q) {
        int m = m0 + wr + i * 16 + rq + q;
        if (m >= M) continue;
        float v = acc[i][j][q];
        if constexpr (SPLIT) {
          v = (n < Nvalid) ? fmaxf(v + bias[n], 0.0f) : 0.0f;
          unsigned short h = f2bf(v);
          unsigned short l = f2bf(v - bf2f(h));
          Ch[(size_t)m * 256 + n] = h;
          Cl[(size_t)m * 256 + n] = l;
        } else {
          Cf[(size_t)m * 128 + n] = v;
        }
      }
    }
  }
}

// ---------------- fused relu(agg2+b2) + segmented max-pool ----------------

constexpr int POOL_CHUNK = 256;

__global__ void k_pool(const float* __restrict__ agg2, const float* __restrict__ b2,
                       const int* __restrict__ batch, float* pooled) {
  int f = threadIdx.x;
  if (f >= F2) return;
  float b = b2[f];
  int n0 = blockIdx.x * POOL_CHUNK;
  int n1 = min(n0 + POOL_CHUNK, NN);
  int curg = -1;
  float vmax = 0.0f;
  for (int n = n0; n < n1; ++n) {
    int g = batch[n];
    if (g != curg) {
      if (curg >= 0 && vmax > 0.0f)
        atomicMax((int*)&pooled[curg * F2 + f], __float_as_int(vmax));
      curg = g;
      vmax = 0.0f;
    }
    float v = agg2[(size_t)n * 128 + f] + b;
    vmax = fmaxf(vmax, v);
  }
  if (curg >= 0 && vmax > 0.0f)
    atomicMax((int*)&pooled[curg * F2 + f], __float_as_int(vmax));
}

// ---------------- tiny MLP head: 115 -> 64 -> 32 -> 1 ----------------

__global__ void k_mlp(const float* __restrict__ pooled,
                      const float* __restrict__ Wg, const float* __restrict__ bg,
                      const float* __restrict__ Wf, const float* __restrict__ bf,
                      const float* __restrict__ Wo, const float* __restrict__ bo,
                      float* __restrict__ out) {
  __shared__ float sp[F2];
  __shared__ float sg[64];
  __shared__ float sf[32];
  int g = blockIdx.x, t = threadIdx.x;
  for (int f = t; f < F2; f += 64) sp[f] = pooled[g * F2 + f];
  __syncthreads();
  float a = bg[t];
  for (int k = 0; k < F2; ++k) a += sp[k] * Wg[k * 64 + t];
  sg[t] = fmaxf(a, 0.0f);
  __syncthreads();
  if (t < 32) {
    float c = bf[t];
    for (int k = 0; k < 64; ++k) c += sg[k] * Wf[k * 32 + t];
    sf[t] = fmaxf(c, 0.0f);
  }
  __syncthreads();
  if (t == 0) {
    float c = bo[0];
    for (int k = 0; k < 32; ++k) c += sf[k] * Wo[k];
    out[g] = c;
  }
}

// ---------------- launch ----------------

extern "C" void kernel_launch(void* const* d_in, const int* in_sizes, int n_in,
                              void* d_out, int out_size, void* d_ws, size_t ws_size,
                              hipStream_t stream) {
  const float* x  = (const float*)d_in[0];
  const int* ei   = (const int*)d_in[1];
  const int* batch = (const int*)d_in[2];
  const float* W1 = (const float*)d_in[3];
  const float* b1 = (const float*)d_in[4];
  const float* W2 = (const float*)d_in[5];
  const float* b2 = (const float*)d_in[6];
  const float* Wg = (const float*)d_in[7];
  const float* bg = (const float*)d_in[8];
  const float* Wf = (const float*)d_in[9];
  const float* bf = (const float*)d_in[10];
  const float* Wo = (const float*)d_in[11];
  const float* bo = (const float*)d_in[12];
  const int* src = ei;
  const int* dst = ei + NE;

  char* p = (char*)d_ws;
  auto alloc4 = [&](size_t units) { void* r = p; p += units * 4; return r; };
  float* dinv  = (float*)alloc4(100224);
  int* cnt     = (int*)alloc4(100224);
  int* off     = (int*)alloc4(100352);
  int* cur     = (int*)alloc4(100224);
  int* bsum    = (int*)alloc4(128);
  int* srcs    = (int*)alloc4(NE);
  float* norms = (float*)alloc4(NE);
  unsigned short* A1h = (unsigned short*)alloc4((size_t)MPAD * 128 / 2);  // 25.6MB
  unsigned short* A1l = (unsigned short*)alloc4((size_t)MPAD * 128 / 2);
  unsigned short* Bt1h = (unsigned short*)alloc4(256 * 128 / 2);
  unsigned short* Bt1l = (unsigned short*)alloc4(256 * 128 / 2);
  unsigned short* Bt2h = (unsigned short*)alloc4(128 * 256 / 2);
  unsigned short* Bt2l = (unsigned short*)alloc4(128 * 256 / 2);
  unsigned short* h1h = (unsigned short*)alloc4((size_t)MPAD * 256 / 2);  // 51.2MB
  unsigned short* h1l = (unsigned short*)alloc4((size_t)MPAD * 256 / 2);
  float* t2     = (float*)alloc4((size_t)MPAD * 128);                     // 51.2MB
  float* pooled = (float*)alloc4((size_t)NG * F2);
  float* agg2   = (float*)A1h;  // alias: A1 dead after GEMM1

  hipMemsetAsync(cnt, 0, 100224 * sizeof(int), stream);
  hipMemsetAsync(pooled, 0, (size_t)NG * F2 * sizeof(float), stream);

  // CSR build (shared by both conv layers)
  k_count<<<(NE + 255) / 256, 256, 0, stream>>>(dst, cnt);
  k_dinv<<<(NN + 255) / 256, 256, 0, stream>>>(cnt, dinv);
  k_scan1<<<NB, SCAN_T, 0, stream>>>(cnt, off, bsum);
  k_scan2<<<1, 64, 0, stream>>>(bsum);
  k_scan3<<<(NN + 256) / 256, 256, 0, stream>>>(off, bsum, cur);
  k_place<<<(NE + 255) / 256, 256, 0, stream>>>(src, dst, dinv, cur, srcs, norms);

  // weight prep (bf16 hi/lo, transposed, zero-padded)
  k_prepB<<<256, 128, 0, stream>>>(W1, Bt1h, Bt1l, F0, F1, 128);
  k_prepB<<<128, 256, 0, stream>>>(W2, Bt2h, Bt2l, F1, F2, 256);

  // layer 1: aggregate X via gather (bf16-split output), then MFMA GEMM -> h1 hi/lo
  k_gather_split<<<NN, 128, 0, stream>>>(x, dinv, off, srcs, norms, A1h, A1l);
  k_mgemm<2, true><<<dim3(2, MPAD / 128), 256, 0, stream>>>(
      A1h, A1l, Bt1h, Bt1l, b1, F1, NN, nullptr, h1h, h1l);

  // layer 2: MFMA GEMM -> t2 (f32), then aggregate via gather
  k_mgemm<4, false><<<dim3(1, MPAD / 128), 256, 0, stream>>>(
      h1h, h1l, Bt2h, Bt2l, nullptr, F2, NN, t2, nullptr, nullptr);
  k_gather_f32<<<NN, 128, 0, stream>>>(t2, dinv, off, srcs, norms, agg2);

  // fused relu(agg2 + b2) + per-graph max pool
  k_pool<<<(NN + POOL_CHUNK - 1) / POOL_CHUNK, 128, 0, stream>>>(agg2, b2, batch, pooled);

  // head MLP
  k_mlp<<<NG, 64, 0, stream>>>(pooled, Wg, bg, Wf, bf, Wo, bo, (float*)d_out);
}